// Round 7
// baseline (242.729 us; speedup 1.0000x reference)
//
#include <hip/hip_runtime.h>
#include <hip/hip_cooperative_groups.h>
#include <hip/hip_bf16.h>

namespace cg = cooperative_groups;

// Problem constants (match reference setup_inputs)
static constexpr int N = 100000;
static constexpr int E = 600000;
static constexpr int D = 128;
static constexpr int B = 10000;
static constexpr int C = 32;
static constexpr int NB = (N + 1023) / 1024;               // 98 scan chunks per array
static constexpr int EBC = (E + 255) / 256;                // 2344 edge vblocks
static constexpr int TOUCHB = (N * (D / 4) + 255) / 256;   // 12500 touch vblocks
static constexpr int P2TOT = EBC + 81 + TOUCHB;            // edge + swizzle + touch

typedef __attribute__((ext_vector_type(8))) short short8;   // 8 bf16 (4 VGPRs)
typedef __attribute__((ext_vector_type(4))) float f32x4;    // MFMA acc

// bf16 RNE helpers (bit-level, no NaN inputs here)
static __device__ __forceinline__ unsigned short f2bf(float f) {
    unsigned u = __float_as_uint(f);
    unsigned r = (u + 0x7FFFu + ((u >> 16) & 1u)) >> 16;
    return (unsigned short)r;
}
static __device__ __forceinline__ float bf2f(unsigned short h) {
    return __uint_as_float(((unsigned)h) << 16);
}

// split 8 consecutive floats into hi/lo bf16 fragments
static __device__ __forceinline__ void split8(const float4 v0, const float4 v1,
                                              short8& h, short8& l) {
    const float f[8] = {v0.x, v0.y, v0.z, v0.w, v1.x, v1.y, v1.z, v1.w};
    #pragma unroll
    for (int i = 0; i < 8; ++i) {
        unsigned short hh = f2bf(f[i]);
        h[i] = (short)hh;
        l[i] = (short)f2bf(f[i] - bf2f(hh));
    }
}

// ---------------- label marking ----------------
__global__ void lab_k(const int* __restrict__ label_pos, int* __restrict__ labflag,
                      int* __restrict__ flag, int nlab) {
    int i = blockIdx.x * blockDim.x + threadIdx.x;
    if (i < nlab) {
        int v = label_pos[i];
        labflag[v] = 1;
        flag[v] = 1;   // labels are in U
    }
}

// ================= R5 fallback path kernels (verbatim, verified 241 us) =================

__global__ __launch_bounds__(256) void deg_swz_k(
    const int* __restrict__ src, const int* __restrict__ dst,
    const int* __restrict__ labflag,
    int* __restrict__ deg, int* __restrict__ flag, int nE, int EB,
    const float* W0, const float* W1, const float* W2, const float* W3,
    const float* W4, const float* W5,
    unsigned short* __restrict__ out,
    const float* __restrict__ xtouch, float* __restrict__ sink) {
    if ((int)blockIdx.x < EB) {
        int e = blockIdx.x * 256 + threadIdx.x;
        if (e < nE) {
            int d = dst[e];
            atomicAdd(&deg[d], 1);
            if (labflag[d]) flag[src[e]] = 1;   // benign race, all write 1
        }
        return;
    }
    if ((int)blockIdx.x < EB + 80) {
        const int sb = blockIdx.x - EB;          // 0..79
        const int m = sb >> 4;                   // 0..4
        const int chunk = sb & 15;
        const float* W = (m == 0) ? W0 : (m == 1) ? W1 : (m == 2) ? W2
                       : (m == 3) ? W3 : W4;
        unsigned short* o = out + (size_t)m * 32768;
        #pragma unroll
        for (int it = 0; it < 4; ++it) {
            int f = chunk * 1024 + it * 256 + threadIdx.x;   // 0..16383
            int j = f & 7;
            int lane = (f >> 3) & 63;
            int fi = f >> 9;                                 // ko*8+no
            int k = (fi >> 3) * 32 + (lane >> 4) * 8 + j;
            int n = (fi & 7) * 16 + (lane & 15);
            float a = W[k * 128 + n];
            unsigned short h = f2bf(a);
            o[f] = h;
            o[16384 + f] = f2bf(a - bf2f(h));
        }
        return;
    }
    if ((int)blockIdx.x == EB + 80) {
        unsigned short* o2 = out + (size_t)5 * 32768;
        #pragma unroll
        for (int it = 0; it < 16; ++it) {
            int f = it * 256 + threadIdx.x;   // 0..4095
            int j = f & 7;
            int lane = (f >> 3) & 63;
            int fi = f >> 9;                  // 0..7 = kp*2+no2
            int k = (fi >> 1) * 32 + (lane >> 4) * 8 + j;
            int n = (fi & 1) * 16 + (lane & 15);
            float a = W5[k * 32 + n];
            unsigned short h = f2bf(a);
            o2[f] = h;
            o2[4096 + f] = f2bf(a - bf2f(h));
        }
        return;
    }
    // ---- L3 warm touch of node_state
    const int f4 = (blockIdx.x - (EB + 81)) * 256 + threadIdx.x;
    if (f4 < N * (D / 4)) {
        float4 v = reinterpret_cast<const float4*>(xtouch)[f4];
        float s = v.x + v.y + v.z + v.w;
        if (s > 1e30f) *sink = s;   // data-dependent, never taken: keeps the loads
    }
}

__global__ __launch_bounds__(256) void scan1m_k(const int* __restrict__ deg,
                                                const int* __restrict__ flag,
                                                int* __restrict__ bsum, int n) {
    __shared__ int lsum[256];
    const int t = threadIdx.x;
    const bool isdeg = (int)blockIdx.x < NB;
    const int bloc = isdeg ? blockIdx.x : blockIdx.x - NB;
    const int* v = isdeg ? deg : flag;
    const int base = bloc * 1024 + t * 4;
    int s = 0;
    #pragma unroll
    for (int i = 0; i < 4; ++i) {
        int idx = base + i;
        if (idx < n) s += v[idx];
    }
    lsum[t] = s;
    __syncthreads();
    for (int off = 128; off > 0; off >>= 1) {
        if (t < off) lsum[t] += lsum[t + off];
        __syncthreads();
    }
    if (t == 0) bsum[blockIdx.x] = lsum[0];
}

__global__ __launch_bounds__(256) void scan3m_k(
    const int* __restrict__ deg, const int* __restrict__ flag,
    const int* __restrict__ bsum,
    int* __restrict__ roff, int* __restrict__ cur,
    int* __restrict__ map, int* __restrict__ ulist, int* __restrict__ ucnt,
    int n)
{
    __shared__ int sb[128];
    __shared__ int lsum[256];
    const int t = threadIdx.x;
    const bool isdeg = (int)blockIdx.x < NB;
    const int bloc = isdeg ? blockIdx.x : blockIdx.x - NB;
    const int* bs = isdeg ? bsum : bsum + NB;
    const int* v  = isdeg ? deg : flag;

    if (t < 128) sb[t] = (t < NB) ? bs[t] : 0;
    __syncthreads();
    for (int off = 1; off < 128; off <<= 1) {
        int u = (t < 128 && t >= off) ? sb[t - off] : 0;
        __syncthreads();
        if (t < 128) sb[t] += u;
        __syncthreads();
    }
    const int boff = (bloc == 0) ? 0 : sb[bloc - 1];
    if (bloc == 0 && t == 0) {
        if (isdeg) roff[n] = sb[NB - 1];
        else *ucnt = sb[NB - 1];
    }

    const int base = bloc * 1024 + t * 4;
    int d[4];
    int s = 0;
    #pragma unroll
    for (int i = 0; i < 4; ++i) {
        int idx = base + i;
        d[i] = (idx < n) ? v[idx] : 0;
        s += d[i];
    }
    lsum[t] = s;
    __syncthreads();
    for (int off = 1; off < 256; off <<= 1) {
        int u = (t >= off) ? lsum[t - off] : 0;
        __syncthreads();
        lsum[t] += u;
        __syncthreads();
    }
    int run = boff + lsum[t] - s;
    #pragma unroll
    for (int i = 0; i < 4; ++i) {
        int idx = base + i;
        if (idx < n) {
            if (isdeg) {
                roff[idx] = run;
                cur[idx]  = run;
                run += d[i];
            } else if (d[i]) {
                map[idx] = run;
                ulist[run] = idx;
                ++run;
            }
        }
    }
}

__global__ void fill_k(const int* __restrict__ src, const int* __restrict__ dst,
                       const int* __restrict__ flag,
                       int* __restrict__ cur, int* __restrict__ csr_src, int nE) {
    int e = blockIdx.x * blockDim.x + threadIdx.x;
    if (e < nE) {
        int d = dst[e];
        if (flag[d]) {
            int p = atomicAdd(&cur[d], 1);
            csr_src[p] = src[e];
        }
    }
}

template <bool GATHER, bool MAP>
__global__ __launch_bounds__(256) void gather_mean_k(
    const float* __restrict__ x, const int* __restrict__ roff,
    const int* __restrict__ csr_src, const int* __restrict__ rows,
    const int* __restrict__ map, const int* __restrict__ nrows_ptr,
    float* __restrict__ out, int nrows_max) {
    const int nrows = nrows_ptr ? nrows_ptr[0] : nrows_max;
    const int w = blockIdx.x * (blockDim.x >> 6) + (threadIdx.x >> 6);
    if (w >= nrows) return;
    const int lane = threadIdx.x & 63;
    const int n  = GATHER ? rows[w] : w;
    const int jb = roff[n];
    const int je = roff[n + 1];
    const float* xb = x + lane * 2;

    float ax = 0.f, ay = 0.f;
    int j = jb;
    for (; j + 4 <= je; j += 4) {
        int s0 = csr_src[j + 0];
        int s1 = csr_src[j + 1];
        int s2 = csr_src[j + 2];
        int s3 = csr_src[j + 3];
        if (MAP) { s0 = map[s0]; s1 = map[s1]; s2 = map[s2]; s3 = map[s3]; }
        float2 v0 = *reinterpret_cast<const float2*>(xb + (size_t)s0 * D);
        float2 v1 = *reinterpret_cast<const float2*>(xb + (size_t)s1 * D);
        float2 v2 = *reinterpret_cast<const float2*>(xb + (size_t)s2 * D);
        float2 v3 = *reinterpret_cast<const float2*>(xb + (size_t)s3 * D);
        ax += v0.x + v1.x + v2.x + v3.x;
        ay += v0.y + v1.y + v2.y + v3.y;
    }
    for (; j < je; ++j) {
        int s = csr_src[j];
        if (MAP) s = map[s];
        float2 v = *reinterpret_cast<const float2*>(xb + (size_t)s * D);
        ax += v.x;
        ay += v.y;
    }
    const float inv = 1.0f / fmaxf((float)(je - jb), 1.0f);
    *reinterpret_cast<float2*>(out + (size_t)w * D + lane * 2) =
        make_float2(ax * inv, ay * inv);
}

template <bool GATHER, bool MAP>
__global__ __launch_bounds__(256, 6) void sage_mfma_k(
    const float* __restrict__ mean, const float* __restrict__ xsrc,
    const int* __restrict__ rows, const int* __restrict__ map,
    const int* __restrict__ nrows_ptr,
    const unsigned short* __restrict__ WlSw, const unsigned short* __restrict__ WrSw,
    const float* __restrict__ bl, float* __restrict__ xout, int nrows_max)
{
    const int nrows = nrows_ptr ? nrows_ptr[0] : nrows_max;
    const int rb = blockIdx.x * 32;
    if (rb >= nrows) return;

    const int t = threadIdx.x;
    const int wrow = (t >> 6) & 1;
    const int wcol = t >> 7;
    const int lane = t & 63;
    const int mcol = lane & 15;
    const int q = lane >> 4;
    const int r = rb + wrow * 16 + mcol;

    f32x4 acc[4];
    #pragma unroll
    for (int no = 0; no < 4; ++no) acc[no] = (f32x4){0.f, 0.f, 0.f, 0.f};

    size_t gidx = 0;
    if (r < nrows) {
        int g = GATHER ? rows[r] : r;
        if (MAP) g = map[g];
        gidx = (size_t)g;
    }

    #pragma unroll
    for (int br = 0; br < 2; ++br) {
        const unsigned short* __restrict__ Wm = br ? WrSw : WlSw;
        #pragma unroll
        for (int kp = 0; kp < 4; ++kp) {
            short8 aH, aL;
            {
                float4 v0 = make_float4(0.f, 0.f, 0.f, 0.f);
                float4 v1 = make_float4(0.f, 0.f, 0.f, 0.f);
                if (r < nrows) {
                    const float* p = (br == 0)
                        ? mean + (size_t)r * D + kp * 32 + q * 8
                        : xsrc + gidx * D + kp * 32 + q * 8;
                    v0 = *reinterpret_cast<const float4*>(p);
                    v1 = *reinterpret_cast<const float4*>(p + 4);
                }
                split8(v0, v1, aH, aL);
            }
            #pragma unroll
            for (int no = 0; no < 4; ++no) {
                const size_t fo = ((size_t)(kp * 8 + wcol * 4 + no) * 64 + lane) * 8;
                short8 bh = *reinterpret_cast<const short8*>(Wm + fo);
                short8 bo = *reinterpret_cast<const short8*>(Wm + 16384 + fo);
                acc[no] = __builtin_amdgcn_mfma_f32_16x16x32_bf16(aH, bh, acc[no], 0, 0, 0);
                acc[no] = __builtin_amdgcn_mfma_f32_16x16x32_bf16(aL, bh, acc[no], 0, 0, 0);
                acc[no] = __builtin_amdgcn_mfma_f32_16x16x32_bf16(aH, bo, acc[no], 0, 0, 0);
            }
        }
    }

    #pragma unroll
    for (int no = 0; no < 4; ++no) {
        const int col = wcol * 64 + no * 16 + mcol;
        const float bias = bl[col];
        #pragma unroll
        for (int ri = 0; ri < 4; ++ri) {
            const int row = rb + wrow * 16 + q * 4 + ri;
            if (row < nrows)
                xout[(size_t)row * D + col] = fmaxf(acc[no][ri] + bias, 0.f);
        }
    }
}

__global__ __launch_bounds__(256) void sage2_cls_k(
    const float* __restrict__ mean, const float* __restrict__ x1c,
    const int* __restrict__ label_pos, const int* __restrict__ map,
    const unsigned short* __restrict__ WlSw, const unsigned short* __restrict__ WrSw,
    const float* __restrict__ bl,
    const unsigned short* __restrict__ Wc1Sw, const float* __restrict__ bc1,
    const unsigned short* __restrict__ Wc2Sw, const float* __restrict__ bc2,
    float* __restrict__ out, int nrows)
{
    __shared__ alignas(16) float Xs[32][132];
    __shared__ alignas(16) float Hs[32][132];
    const int rb = blockIdx.x * 32;
    const int t = threadIdx.x;
    const int wrow = (t >> 6) & 1;
    const int wcol = t >> 7;
    const int lane = t & 63;
    const int mcol = lane & 15;
    const int q = lane >> 4;
    const int r = rb + wrow * 16 + mcol;

    f32x4 acc[4];
    #pragma unroll
    for (int no = 0; no < 4; ++no) acc[no] = (f32x4){0.f, 0.f, 0.f, 0.f};

    size_t gidx = 0;
    if (r < nrows) gidx = (size_t)map[label_pos[r]];

    #pragma unroll
    for (int br = 0; br < 2; ++br) {
        const unsigned short* __restrict__ Wm = br ? WrSw : WlSw;
        #pragma unroll
        for (int kp = 0; kp < 4; ++kp) {
            short8 aH, aL;
            {
                float4 v0 = make_float4(0.f, 0.f, 0.f, 0.f);
                float4 v1 = make_float4(0.f, 0.f, 0.f, 0.f);
                if (r < nrows) {
                    const float* p = (br == 0)
                        ? mean + (size_t)r * D + kp * 32 + q * 8
                        : x1c + gidx * D + kp * 32 + q * 8;
                    v0 = *reinterpret_cast<const float4*>(p);
                    v1 = *reinterpret_cast<const float4*>(p + 4);
                }
                split8(v0, v1, aH, aL);
            }
            #pragma unroll
            for (int no = 0; no < 4; ++no) {
                const size_t fo = ((size_t)(kp * 8 + wcol * 4 + no) * 64 + lane) * 8;
                short8 bh = *reinterpret_cast<const short8*>(Wm + fo);
                short8 bo = *reinterpret_cast<const short8*>(Wm + 16384 + fo);
                acc[no] = __builtin_amdgcn_mfma_f32_16x16x32_bf16(aH, bh, acc[no], 0, 0, 0);
                acc[no] = __builtin_amdgcn_mfma_f32_16x16x32_bf16(aL, bh, acc[no], 0, 0, 0);
                acc[no] = __builtin_amdgcn_mfma_f32_16x16x32_bf16(aH, bo, acc[no], 0, 0, 0);
            }
        }
    }

    #pragma unroll
    for (int no = 0; no < 4; ++no) {
        const int col = wcol * 64 + no * 16 + mcol;
        const float bias = bl[col];
        #pragma unroll
        for (int ri = 0; ri < 4; ++ri) {
            const int lrow = wrow * 16 + q * 4 + ri;
            Xs[lrow][col] = fmaxf(acc[no][ri] + bias, 0.f);
        }
    }
    __syncthreads();

    {
        f32x4 acc2[4];
        #pragma unroll
        for (int no = 0; no < 4; ++no) acc2[no] = (f32x4){0.f, 0.f, 0.f, 0.f};

        #pragma unroll
        for (int kp = 0; kp < 4; ++kp) {
            short8 aH, aL;
            {
                const float* p = &Xs[wrow * 16 + mcol][kp * 32 + q * 8];
                float4 v0 = *reinterpret_cast<const float4*>(p);
                float4 v1 = *reinterpret_cast<const float4*>(p + 4);
                split8(v0, v1, aH, aL);
            }
            #pragma unroll
            for (int no = 0; no < 4; ++no) {
                const size_t fo = ((size_t)(kp * 8 + wcol * 4 + no) * 64 + lane) * 8;
                short8 bh = *reinterpret_cast<const short8*>(Wc1Sw + fo);
                short8 bo = *reinterpret_cast<const short8*>(Wc1Sw + 16384 + fo);
                acc2[no] = __builtin_amdgcn_mfma_f32_16x16x32_bf16(aH, bh, acc2[no], 0, 0, 0);
                acc2[no] = __builtin_amdgcn_mfma_f32_16x16x32_bf16(aL, bh, acc2[no], 0, 0, 0);
                acc2[no] = __builtin_amdgcn_mfma_f32_16x16x32_bf16(aH, bo, acc2[no], 0, 0, 0);
            }
        }
        #pragma unroll
        for (int no = 0; no < 4; ++no) {
            const int col = wcol * 64 + no * 16 + mcol;
            const float bias = bc1[col];
            #pragma unroll
            for (int ri = 0; ri < 4; ++ri) {
                const int lrow = wrow * 16 + q * 4 + ri;
                Hs[lrow][col] = fmaxf(acc2[no][ri] + bias, 0.0f);
            }
        }
    }
    __syncthreads();

    {
        f32x4 acc3 = (f32x4){0.f, 0.f, 0.f, 0.f};
        #pragma unroll
        for (int kp = 0; kp < 4; ++kp) {
            short8 aH, aL;
            {
                const float* p = &Hs[wrow * 16 + mcol][kp * 32 + q * 8];
                float4 v0 = *reinterpret_cast<const float4*>(p);
                float4 v1 = *reinterpret_cast<const float4*>(p + 4);
                split8(v0, v1, aH, aL);
            }
            const size_t fo = ((size_t)(kp * 2 + wcol) * 64 + lane) * 8;
            short8 bh = *reinterpret_cast<const short8*>(Wc2Sw + fo);
            short8 bo = *reinterpret_cast<const short8*>(Wc2Sw + 4096 + fo);
            acc3 = __builtin_amdgcn_mfma_f32_16x16x32_bf16(aH, bh, acc3, 0, 0, 0);
            acc3 = __builtin_amdgcn_mfma_f32_16x16x32_bf16(aL, bh, acc3, 0, 0, 0);
            acc3 = __builtin_amdgcn_mfma_f32_16x16x32_bf16(aH, bo, acc3, 0, 0, 0);
        }
        const int col = wcol * 16 + mcol;
        const float b2 = bc2[col];
        #pragma unroll
        for (int ri = 0; ri < 4; ++ri) {
            const int row = rb + wrow * 16 + q * 4 + ri;
            if (row < nrows) out[(size_t)row * C + col] = acc3[ri] + b2;
        }
    }
}

// ================= cooperative mega kernel (everything after lab_k) =================
struct MegaArgs {
    const int* src; const int* dst; const int* label_pos;
    const float* x;
    const float* W0; const float* W1; const float* W2; const float* W3;
    const float* W4; const float* W5;
    const float* b1l; const float* b2l; const float* bc1; const float* bc2;
    unsigned short* Wsw;
    int* deg; int* flag; const int* labflag;
    int* ucnt;
    int* roff; int* cur; int* csr; int* map; int* ulist;
    int* bsum; int* boff;
    float* sink;
    float* x1c; float* bufA;
    float* out;
};

__global__ __launch_bounds__(256) void mega_k(MegaArgs A) {
    cg::grid_group grid = cg::this_grid();
    const int t = threadIdx.x;
    const int nblk = gridDim.x;
    const int lane = t & 63;
    const int wl = t >> 6;
    const int wrow = (t >> 6) & 1;
    const int wcol = t >> 7;
    const int mcol = lane & 15;
    const int q = lane >> 4;

    __shared__ alignas(16) float Xs[32][132];
    __shared__ alignas(16) float Hs[32][132];
    __shared__ int lsum[256];

    // P2: edge pass + weight swizzle + L3 touch
    for (int vb = blockIdx.x; vb < P2TOT; vb += nblk) {
        if (vb < EBC) {
            int e = vb * 256 + t;
            if (e < E) {
                int d = A.dst[e];
                atomicAdd(&A.deg[d], 1);
                if (A.labflag[d]) A.flag[A.src[e]] = 1;
            }
        } else if (vb < EBC + 80) {
            const int sb = vb - EBC;
            const int m = sb >> 4;
            const int chunk = sb & 15;
            const float* W = (m == 0) ? A.W0 : (m == 1) ? A.W1 : (m == 2) ? A.W2
                           : (m == 3) ? A.W3 : A.W4;
            unsigned short* o = A.Wsw + (size_t)m * 32768;
            #pragma unroll
            for (int it = 0; it < 4; ++it) {
                int f = chunk * 1024 + it * 256 + t;
                int j = f & 7;
                int ln = (f >> 3) & 63;
                int fi = f >> 9;
                int k = (fi >> 3) * 32 + (ln >> 4) * 8 + j;
                int n = (fi & 7) * 16 + (ln & 15);
                float a = W[k * 128 + n];
                unsigned short h = f2bf(a);
                o[f] = h;
                o[16384 + f] = f2bf(a - bf2f(h));
            }
        } else if (vb == EBC + 80) {
            unsigned short* o2 = A.Wsw + (size_t)5 * 32768;
            #pragma unroll
            for (int it = 0; it < 16; ++it) {
                int f = it * 256 + t;
                int j = f & 7;
                int ln = (f >> 3) & 63;
                int fi = f >> 9;
                int k = (fi >> 1) * 32 + (ln >> 4) * 8 + j;
                int n = (fi & 1) * 16 + (ln & 15);
                float a = A.W5[k * 32 + n];
                unsigned short h = f2bf(a);
                o2[f] = h;
                o2[4096 + f] = f2bf(a - bf2f(h));
            }
        } else {
            const int f4 = (vb - (EBC + 81)) * 256 + t;
            if (f4 < N * (D / 4)) {
                float4 v = reinterpret_cast<const float4*>(A.x)[f4];
                float s = v.x + v.y + v.z + v.w;
                if (s > 1e30f) *A.sink = s;
            }
        }
    }
    grid.sync();

    // P3: chunk sums (deg gated by flag -> compact CSR); registers persist to P5
    int d0 = 0, d1 = 0, d2 = 0, d3 = 0, tpre = 0;
    const bool isScan = (int)blockIdx.x < 2 * NB;
    const bool isdeg = (int)blockIdx.x < NB;
    if (isScan) {
        const int bloc = isdeg ? blockIdx.x : blockIdx.x - NB;
        const int base = bloc * 1024 + t * 4;
        int s = 0;
        int dd[4];
        #pragma unroll
        for (int i = 0; i < 4; ++i) {
            int idx = base + i;
            int v = 0;
            if (idx < N) v = isdeg ? (A.flag[idx] ? A.deg[idx] : 0) : A.flag[idx];
            dd[i] = v; s += v;
        }
        d0 = dd[0]; d1 = dd[1]; d2 = dd[2]; d3 = dd[3];
        lsum[t] = s;
        __syncthreads();
        for (int off = 1; off < 256; off <<= 1) {
            int u = (t >= off) ? lsum[t - off] : 0;
            __syncthreads();
            lsum[t] += u;
            __syncthreads();
        }
        tpre = lsum[t] - s;
        if (t == 0) A.bsum[blockIdx.x] = lsum[255];
    }
    grid.sync();

    // P4: block 0 serial exclusive scans
    if (blockIdx.x == 0) {
        if (t == 0) {
            int r = 0;
            for (int b = 0; b < NB; ++b) { int v = A.bsum[b]; A.boff[b] = r; r += v; }
            A.roff[N] = r;
        }
        if (t == 1) {
            int r = 0;
            for (int b = NB; b < 2 * NB; ++b) { int v = A.bsum[b]; A.boff[b] = r; r += v; }
            *A.ucnt = r;
        }
    }
    grid.sync();
    const int ucv = *A.ucnt;

    // P5: apply scan
    if (isScan) {
        const int bloc = isdeg ? blockIdx.x : blockIdx.x - NB;
        const int base = bloc * 1024 + t * 4;
        int run = A.boff[blockIdx.x] + tpre;
        int dd[4] = {d0, d1, d2, d3};
        #pragma unroll
        for (int i = 0; i < 4; ++i) {
            int idx = base + i;
            if (idx < N) {
                if (isdeg) {
                    A.roff[idx] = run;
                    A.cur[idx]  = run;
                    run += dd[i];
                } else if (dd[i]) {
                    A.map[idx] = run;
                    A.ulist[run] = idx;
                    ++run;
                }
            }
        }
    }
    grid.sync();

    // P6: CSR fill (gated)
    for (int vb = blockIdx.x; vb < EBC; vb += nblk) {
        int e = vb * 256 + t;
        if (e < E) {
            int d = A.dst[e];
            if (A.flag[d]) {
                int p = atomicAdd(&A.cur[d], 1);
                A.csr[p] = A.src[e];
            }
        }
    }
    grid.sync();

    // P7: gather-mean layer 1
    {
        const float* xb = A.x + lane * 2;
        const int nw = nblk * 4;
        for (int w = blockIdx.x * 4 + wl; w < ucv; w += nw) {
            const int n = A.ulist[w];
            const int jb = A.roff[n];
            const int je = A.roff[n + 1];
            float ax = 0.f, ay = 0.f;
            int j = jb;
            for (; j + 4 <= je; j += 4) {
                int s0 = A.csr[j + 0];
                int s1 = A.csr[j + 1];
                int s2 = A.csr[j + 2];
                int s3 = A.csr[j + 3];
                float2 v0 = *reinterpret_cast<const float2*>(xb + (size_t)s0 * D);
                float2 v1 = *reinterpret_cast<const float2*>(xb + (size_t)s1 * D);
                float2 v2 = *reinterpret_cast<const float2*>(xb + (size_t)s2 * D);
                float2 v3 = *reinterpret_cast<const float2*>(xb + (size_t)s3 * D);
                ax += v0.x + v1.x + v2.x + v3.x;
                ay += v0.y + v1.y + v2.y + v3.y;
            }
            for (; j < je; ++j) {
                int s = A.csr[j];
                float2 v = *reinterpret_cast<const float2*>(xb + (size_t)s * D);
                ax += v.x;
                ay += v.y;
            }
            const float inv = 1.0f / fmaxf((float)(je - jb), 1.0f);
            *reinterpret_cast<float2*>(A.bufA + (size_t)w * D + lane * 2) =
                make_float2(ax * inv, ay * inv);
        }
    }
    grid.sync();

    // P8: SAGE layer 1 MFMA -> x1c
    {
        const unsigned short* WlSw = A.Wsw;
        const unsigned short* WrSw = A.Wsw + 32768;
        const int ntile = (ucv + 31) / 32;
        for (int tile = blockIdx.x; tile < ntile; tile += nblk) {
            const int rb = tile * 32;
            const int r = rb + wrow * 16 + mcol;

            f32x4 acc[4];
            #pragma unroll
            for (int no = 0; no < 4; ++no) acc[no] = (f32x4){0.f, 0.f, 0.f, 0.f};

            size_t gidx = 0;
            if (r < ucv) gidx = (size_t)A.ulist[r];

            #pragma unroll
            for (int br = 0; br < 2; ++br) {
                const unsigned short* Wm = br ? WrSw : WlSw;
                #pragma unroll
                for (int kp = 0; kp < 4; ++kp) {
                    short8 aH, aL;
                    {
                        float4 v0 = make_float4(0.f, 0.f, 0.f, 0.f);
                        float4 v1 = make_float4(0.f, 0.f, 0.f, 0.f);
                        if (r < ucv) {
                            const float* p = (br == 0)
                                ? A.bufA + (size_t)r * D + kp * 32 + q * 8
                                : A.x + gidx * D + kp * 32 + q * 8;
                            v0 = *reinterpret_cast<const float4*>(p);
                            v1 = *reinterpret_cast<const float4*>(p + 4);
                        }
                        split8(v0, v1, aH, aL);
                    }
                    #pragma unroll
                    for (int no = 0; no < 4; ++no) {
                        const size_t fo = ((size_t)(kp * 8 + wcol * 4 + no) * 64 + lane) * 8;
                        short8 bh = *reinterpret_cast<const short8*>(Wm + fo);
                        short8 bo = *reinterpret_cast<const short8*>(Wm + 16384 + fo);
                        acc[no] = __builtin_amdgcn_mfma_f32_16x16x32_bf16(aH, bh, acc[no], 0, 0, 0);
                        acc[no] = __builtin_amdgcn_mfma_f32_16x16x32_bf16(aL, bh, acc[no], 0, 0, 0);
                        acc[no] = __builtin_amdgcn_mfma_f32_16x16x32_bf16(aH, bo, acc[no], 0, 0, 0);
                    }
                }
            }

            #pragma unroll
            for (int no = 0; no < 4; ++no) {
                const int col = wcol * 64 + no * 16 + mcol;
                const float bias = A.b1l[col];
                #pragma unroll
                for (int ri = 0; ri < 4; ++ri) {
                    const int row = rb + wrow * 16 + q * 4 + ri;
                    if (row < ucv)
                        A.x1c[(size_t)row * D + col] = fmaxf(acc[no][ri] + bias, 0.f);
                }
            }
        }
    }
    grid.sync();

    // P9: gather-mean layer 2
    {
        const float* xb = A.x1c + lane * 2;
        const int nw = nblk * 4;
        for (int w = blockIdx.x * 4 + wl; w < B; w += nw) {
            const int n = A.label_pos[w];
            const int jb = A.roff[n];
            const int je = A.roff[n + 1];
            float ax = 0.f, ay = 0.f;
            int j = jb;
            for (; j + 4 <= je; j += 4) {
                int s0 = A.map[A.csr[j + 0]];
                int s1 = A.map[A.csr[j + 1]];
                int s2 = A.map[A.csr[j + 2]];
                int s3 = A.map[A.csr[j + 3]];
                float2 v0 = *reinterpret_cast<const float2*>(xb + (size_t)s0 * D);
                float2 v1 = *reinterpret_cast<const float2*>(xb + (size_t)s1 * D);
                float2 v2 = *reinterpret_cast<const float2*>(xb + (size_t)s2 * D);
                float2 v3 = *reinterpret_cast<const float2*>(xb + (size_t)s3 * D);
                ax += v0.x + v1.x + v2.x + v3.x;
                ay += v0.y + v1.y + v2.y + v3.y;
            }
            for (; j < je; ++j) {
                int s = A.map[A.csr[j]];
                float2 v = *reinterpret_cast<const float2*>(xb + (size_t)s * D);
                ax += v.x;
                ay += v.y;
            }
            const float inv = 1.0f / fmaxf((float)(je - jb), 1.0f);
            *reinterpret_cast<float2*>(A.bufA + (size_t)w * D + lane * 2) =
                make_float2(ax * inv, ay * inv);
        }
    }
    grid.sync();

    // P10: layer 2 + classifier
    {
        const unsigned short* WlSw = A.Wsw + 65536;
        const unsigned short* WrSw = A.Wsw + 98304;
        const unsigned short* Wc1Sw = A.Wsw + 131072;
        const unsigned short* Wc2Sw = A.Wsw + 163840;
        const int ntile = (B + 31) / 32;
        for (int tile = blockIdx.x; tile < ntile; tile += nblk) {
            const int rb = tile * 32;
            const int r = rb + wrow * 16 + mcol;

            f32x4 acc[4];
            #pragma unroll
            for (int no = 0; no < 4; ++no) acc[no] = (f32x4){0.f, 0.f, 0.f, 0.f};

            size_t gidx = 0;
            if (r < B) gidx = (size_t)A.map[A.label_pos[r]];

            #pragma unroll
            for (int br = 0; br < 2; ++br) {
                const unsigned short* Wm = br ? WrSw : WlSw;
                #pragma unroll
                for (int kp = 0; kp < 4; ++kp) {
                    short8 aH, aL;
                    {
                        float4 v0 = make_float4(0.f, 0.f, 0.f, 0.f);
                        float4 v1 = make_float4(0.f, 0.f, 0.f, 0.f);
                        if (r < B) {
                            const float* p = (br == 0)
                                ? A.bufA + (size_t)r * D + kp * 32 + q * 8
                                : A.x1c + gidx * D + kp * 32 + q * 8;
                            v0 = *reinterpret_cast<const float4*>(p);
                            v1 = *reinterpret_cast<const float4*>(p + 4);
                        }
                        split8(v0, v1, aH, aL);
                    }
                    #pragma unroll
                    for (int no = 0; no < 4; ++no) {
                        const size_t fo = ((size_t)(kp * 8 + wcol * 4 + no) * 64 + lane) * 8;
                        short8 bh = *reinterpret_cast<const short8*>(Wm + fo);
                        short8 bo = *reinterpret_cast<const short8*>(Wm + 16384 + fo);
                        acc[no] = __builtin_amdgcn_mfma_f32_16x16x32_bf16(aH, bh, acc[no], 0, 0, 0);
                        acc[no] = __builtin_amdgcn_mfma_f32_16x16x32_bf16(aL, bh, acc[no], 0, 0, 0);
                        acc[no] = __builtin_amdgcn_mfma_f32_16x16x32_bf16(aH, bo, acc[no], 0, 0, 0);
                    }
                }
            }
            #pragma unroll
            for (int no = 0; no < 4; ++no) {
                const int col = wcol * 64 + no * 16 + mcol;
                const float bias = A.b2l[col];
                #pragma unroll
                for (int ri = 0; ri < 4; ++ri) {
                    const int lrow = wrow * 16 + q * 4 + ri;
                    Xs[lrow][col] = fmaxf(acc[no][ri] + bias, 0.f);
                }
            }
            __syncthreads();

            {
                f32x4 acc2[4];
                #pragma unroll
                for (int no = 0; no < 4; ++no) acc2[no] = (f32x4){0.f, 0.f, 0.f, 0.f};

                #pragma unroll
                for (int kp = 0; kp < 4; ++kp) {
                    short8 aH, aL;
                    {
                        const float* p = &Xs[wrow * 16 + mcol][kp * 32 + q * 8];
                        float4 v0 = *reinterpret_cast<const float4*>(p);
                        float4 v1 = *reinterpret_cast<const float4*>(p + 4);
                        split8(v0, v1, aH, aL);
                    }
                    #pragma unroll
                    for (int no = 0; no < 4; ++no) {
                        const size_t fo = ((size_t)(kp * 8 + wcol * 4 + no) * 64 + lane) * 8;
                        short8 bh = *reinterpret_cast<const short8*>(Wc1Sw + fo);
                        short8 bo = *reinterpret_cast<const short8*>(Wc1Sw + 16384 + fo);
                        acc2[no] = __builtin_amdgcn_mfma_f32_16x16x32_bf16(aH, bh, acc2[no], 0, 0, 0);
                        acc2[no] = __builtin_amdgcn_mfma_f32_16x16x32_bf16(aL, bh, acc2[no], 0, 0, 0);
                        acc2[no] = __builtin_amdgcn_mfma_f32_16x16x32_bf16(aH, bo, acc2[no], 0, 0, 0);
                    }
                }
                #pragma unroll
                for (int no = 0; no < 4; ++no) {
                    const int col = wcol * 64 + no * 16 + mcol;
                    const float bias = A.bc1[col];
                    #pragma unroll
                    for (int ri = 0; ri < 4; ++ri) {
                        const int lrow = wrow * 16 + q * 4 + ri;
                        Hs[lrow][col] = fmaxf(acc2[no][ri] + bias, 0.0f);
                    }
                }
            }
            __syncthreads();

            {
                f32x4 acc3 = (f32x4){0.f, 0.f, 0.f, 0.f};
                #pragma unroll
                for (int kp = 0; kp < 4; ++kp) {
                    short8 aH, aL;
                    {
                        const float* p = &Hs[wrow * 16 + mcol][kp * 32 + q * 8];
                        float4 v0 = *reinterpret_cast<const float4*>(p);
                        float4 v1 = *reinterpret_cast<const float4*>(p + 4);
                        split8(v0, v1, aH, aL);
                    }
                    const size_t fo = ((size_t)(kp * 2 + wcol) * 64 + lane) * 8;
                    short8 bh = *reinterpret_cast<const short8*>(Wc2Sw + fo);
                    short8 bo = *reinterpret_cast<const short8*>(Wc2Sw + 4096 + fo);
                    acc3 = __builtin_amdgcn_mfma_f32_16x16x32_bf16(aH, bh, acc3, 0, 0, 0);
                    acc3 = __builtin_amdgcn_mfma_f32_16x16x32_bf16(aL, bh, acc3, 0, 0, 0);
                    acc3 = __builtin_amdgcn_mfma_f32_16x16x32_bf16(aH, bo, acc3, 0, 0, 0);
                }
                const int col = wcol * 16 + mcol;
                const float b2 = A.bc2[col];
                #pragma unroll
                for (int ri = 0; ri < 4; ++ri) {
                    const int row = rb + wrow * 16 + q * 4 + ri;
                    if (row < B) A.out[(size_t)row * C + col] = acc3[ri] + b2;
                }
            }
            __syncthreads();
        }
    }
}

// ---------------- launch ----------------

extern "C" void kernel_launch(void* const* d_in, const int* in_sizes, int n_in,
                              void* d_out, int out_size, void* d_ws, size_t ws_size,
                              hipStream_t stream) {
    const float* node_state = (const float*)d_in[0];
    const int*   edge_index = (const int*)d_in[1];
    const int*   label_pos  = (const int*)d_in[2];
    const float* W1l = (const float*)d_in[3];
    const float* b1l = (const float*)d_in[4];
    const float* W1r = (const float*)d_in[5];
    const float* W2l = (const float*)d_in[6];
    const float* b2l = (const float*)d_in[7];
    const float* W2r = (const float*)d_in[8];
    const float* Wc1 = (const float*)d_in[9];
    const float* bc1 = (const float*)d_in[10];
    const float* Wc2 = (const float*)d_in[11];
    const float* bc2 = (const float*)d_in[12];
    float* out = (float*)d_out;

    const int* src = edge_index;       // edge_index[0]
    const int* dst = edge_index + E;   // edge_index[1]

    // workspace layout (floats first for alignment)
    char* ws = (char*)d_ws;
    float* x1c   = (float*)ws;                    ws += sizeof(float) * (size_t)N * D;
    float* bufA  = (float*)ws;                    ws += sizeof(float) * (size_t)N * D;
    unsigned short* Wsw = (unsigned short*)ws;    ws += sizeof(unsigned short) * (5 * 32768 + 8192);
    int* deg     = (int*)ws;                      ws += sizeof(int) * N;   // |
    int* flag    = (int*)ws;                      ws += sizeof(int) * N;   // | contiguous: one
    int* labflag = (int*)ws;                      ws += sizeof(int) * N;   // | memset
    int* ucnt    = (int*)ws;                      ws += sizeof(int);       // |
    float* sink  = (float*)ws;                    ws += sizeof(float);
    ws += sizeof(int) * 2;                        // pad to 16B
    int* roff    = (int*)ws;                      ws += sizeof(int) * (N + 1);
    int* cur     = (int*)ws;                      ws += sizeof(int) * N;
    int* csr_src = (int*)ws;                      ws += sizeof(int) * E;
    int* map     = (int*)ws;                      ws += sizeof(int) * N;
    int* ulist   = (int*)ws;                      ws += sizeof(int) * N;
    int* bsum    = (int*)ws;                      ws += sizeof(int) * 256;
    int* boff    = (int*)ws;                      ws += sizeof(int) * 256;
    // bufA doubles as mean1c then mean2g
    float* mean1c = bufA;
    float* mean2g = bufA;

    const int TB = 256;
    const int EB = EBC;

    // common prologue (both paths)
    hipMemsetAsync(deg, 0, sizeof(int) * (3 * N + 1), stream);  // deg,flag,labflag,ucnt
    lab_k<<<(B + TB - 1) / TB, TB, 0, stream>>>(label_pos, labflag, flag, B);

    // ---- try the cooperative mega kernel; on ANY failure fall back to R5 path ----
    static int s_coop_ok = -1;   // -1 unknown, 0 no, 1 yes
    static int s_grid = 0;
    if (s_coop_ok == -1) {
        int dev = 0, attr = 0;
        if (hipGetDevice(&dev) != hipSuccess) dev = 0;
        if (hipDeviceGetAttribute(&attr, hipDeviceAttributeCooperativeLaunch, dev)
            != hipSuccess) attr = 0;
        s_coop_ok = attr ? 1 : 0;
    }
    bool launched = false;
    if (s_coop_ok == 1) {
        if (s_grid == 0) {
            int perCU = 0;
            if (hipOccupancyMaxActiveBlocksPerMultiprocessor(&perCU, mega_k, TB, 0)
                != hipSuccess || perCU < 1) perCU = 1;
            s_grid = perCU * 256;                 // 256 CUs on MI355X
            if (s_grid > 2048) s_grid = 2048;
            if (s_grid < 2 * NB) s_grid = 2 * NB; // scan mapping needs 196 blocks
        }
        MegaArgs a;
        a.src = src; a.dst = dst; a.label_pos = label_pos;
        a.x = node_state;
        a.W0 = W1l; a.W1 = W1r; a.W2 = W2l; a.W3 = W2r; a.W4 = Wc1; a.W5 = Wc2;
        a.b1l = b1l; a.b2l = b2l; a.bc1 = bc1; a.bc2 = bc2;
        a.Wsw = Wsw;
        a.deg = deg; a.flag = flag; a.labflag = labflag;
        a.ucnt = ucnt;
        a.roff = roff; a.cur = cur; a.csr = csr_src; a.map = map; a.ulist = ulist;
        a.bsum = bsum; a.boff = boff;
        a.sink = sink;
        a.x1c = x1c; a.bufA = bufA;
        a.out = out;
        void* kargs[] = { &a };
        hipError_t e = hipLaunchCooperativeKernel(mega_k, dim3(s_grid), dim3(TB),
                                                  kargs, 0u, stream);
        if (e == hipSuccess) {
            launched = true;
        } else {
            s_coop_ok = 0;   // never try again this process
        }
    }

    if (!launched) {
        // ======== verified R5 fallback path (241 us) ========
        deg_swz_k<<<EB + 81 + TOUCHB, TB, 0, stream>>>(src, dst, labflag, deg, flag, E, EB,
                                                       W1l, W1r, W2l, W2r, Wc1, Wc2, Wsw,
                                                       node_state, sink);
        scan1m_k<<<2 * NB, 256, 0, stream>>>(deg, flag, bsum, N);
        scan3m_k<<<2 * NB, 256, 0, stream>>>(deg, flag, bsum, roff, cur, map, ulist, ucnt, N);
        fill_k<<<EB, TB, 0, stream>>>(src, dst, flag, cur, csr_src, E);

        gather_mean_k<true, false><<<(N + 3) / 4, TB, 0, stream>>>(
            node_state, roff, csr_src, ulist, nullptr, ucnt, mean1c, N);
        sage_mfma_k<true, false><<<(N + 31) / 32, TB, 0, stream>>>(
            mean1c, node_state, ulist, nullptr, ucnt,
            Wsw, Wsw + 32768, b1l, x1c, N);

        gather_mean_k<true, true><<<(B + 3) / 4, TB, 0, stream>>>(
            x1c, roff, csr_src, label_pos, map, nullptr, mean2g, B);
        sage2_cls_k<<<(B + 31) / 32, TB, 0, stream>>>(
            mean2g, x1c, label_pos, map,
            Wsw + 65536, Wsw + 98304, b2l,
            Wsw + 131072, bc1,
            Wsw + 163840, bc2, out, B);
    }
}